// Round 6
// baseline (89.998 us; speedup 1.0000x reference)
//
#include <hip/hip_runtime.h>
#include <hip/hip_bf16.h>

// GCN layer: out = segment_sum(edge_val * (x@W)[col], row) + bias
// N=100000 nodes, E=640000 edges, D=128.
// y bf16. Pipeline: gemm (MFMA, also inits cursors) -> edge partition
// (256-row buckets) -> LDS-built ELL -> spmm (2-deep node pipeline,
// uint4 gathers) -> overflow fixup.

#define N_NODES 100000
#define N_EDGES 640000
#define D 128
#define ELL_K 16
#define OVF_CAP 8192
#define NB 391          // ceil(N_NODES/256) row buckets
#define BCAP 2048       // per-bucket edge capacity (avg 1638)
#define CHUNK 4096
#define NCHUNKS 157     // ceil(N_EDGES/CHUNK)
#define N_TILES 6250

typedef __attribute__((ext_vector_type(8))) short short8;
typedef __attribute__((ext_vector_type(4))) float f32x4;
typedef __attribute__((ext_vector_type(4))) ushort us4;

__device__ __forceinline__ ushort f2bf(float f) {
    uint u = __float_as_uint(f);
    u += 0x7fff + ((u >> 16) & 1);   // RNE
    return (ushort)(u >> 16);
}
__device__ __forceinline__ float bflo(uint u) { return __uint_as_float(u << 16); }
__device__ __forceinline__ float bfhi(uint u) { return __uint_as_float(u & 0xffff0000u); }

// ---------------- GEMM: y(bf16) = x @ W via MFMA 16x16x32 ----------------
// W^T staged in LDS (XOR-swizzled), whole W held in regs as 8x4 B-fragments.
// Swapped-operand mfma so each lane owns one node-row -> ushort4 stores.
// 512 blocks grid-stride (all resident, one scheduling pass).
// Also zeroes bucketCnt + ovfCnt for the partition kernel.
__global__ __launch_bounds__(256, 2) void gemm_xw(const float* __restrict__ x,
                                                  const float* __restrict__ w,
                                                  ushort* __restrict__ y,
                                                  int* __restrict__ bucketCnt) {
    __shared__ ushort wt[128 * 128];  // 32KB; idx = n*128 + (k ^ ((n&7)<<3))
    const int tid = threadIdx.x;

    int gz = blockIdx.x * 256 + tid;
    if (gz <= NB) bucketCnt[gz] = 0;   // [NB] doubles as ovfCnt

    #pragma unroll
    for (int it = 0; it < 16; ++it) {
        int idx4 = tid + it * 256;        // 4096 float4 = 128x128
        int k = idx4 >> 5;
        int n0 = (idx4 & 31) * 4;
        float4 v = *(const float4*)(w + (size_t)idx4 * 4);
        float vv[4] = {v.x, v.y, v.z, v.w};
        #pragma unroll
        for (int q = 0; q < 4; ++q) {
            int n = n0 + q;
            wt[n * 128 + (k ^ ((n & 7) << 3))] = f2bf(vv[q]);
        }
    }
    __syncthreads();

    const int lane = tid & 63;
    const int l15 = lane & 15;
    const int h = lane >> 4;

    short8 bfr[8][4];
    #pragma unroll
    for (int j = 0; j < 8; ++j) {
        int n = 16 * j + l15;
        #pragma unroll
        for (int ks = 0; ks < 4; ++ks) {
            int k0 = 32 * ks + 8 * h;
            bfr[j][ks] = *(const short8*)&wt[n * 128 + (k0 ^ ((n & 7) << 3))];
        }
    }

    const int waveGlobal = blockIdx.x * 4 + (tid >> 6);
    const int nWaves = gridDim.x * 4;   // 2048

    for (int t = waveGlobal; t < N_TILES; t += nWaves) {
        const float* xr = x + (size_t)(t * 16 + l15) * D;
        float4 xb[8];
        #pragma unroll
        for (int ks = 0; ks < 4; ++ks) {
            xb[2 * ks]     = *(const float4*)(xr + 32 * ks + 8 * h);
            xb[2 * ks + 1] = *(const float4*)(xr + 32 * ks + 8 * h + 4);
        }
        f32x4 acc[8];
        #pragma unroll
        for (int j = 0; j < 8; ++j) acc[j] = (f32x4){0.f, 0.f, 0.f, 0.f};
        #pragma unroll
        for (int ks = 0; ks < 4; ++ks) {
            const float* p0 = (const float*)&xb[2 * ks];
            const float* p1 = (const float*)&xb[2 * ks + 1];
            short8 a;
            a[0] = f2bf(p0[0]); a[1] = f2bf(p0[1]); a[2] = f2bf(p0[2]); a[3] = f2bf(p0[3]);
            a[4] = f2bf(p1[0]); a[5] = f2bf(p1[1]); a[6] = f2bf(p1[2]); a[7] = f2bf(p1[3]);
            #pragma unroll
            for (int j = 0; j < 8; ++j)
                acc[j] = __builtin_amdgcn_mfma_f32_16x16x32_bf16(bfr[j][ks], a, acc[j], 0, 0, 0);
        }
        // node = t*16 + l15, channel = 16j + 4h + r
        ushort* yn = y + (size_t)(t * 16 + l15) * D;
        #pragma unroll
        for (int j = 0; j < 8; ++j) {
            us4 o;
            o.x = f2bf(acc[j][0]); o.y = f2bf(acc[j][1]);
            o.z = f2bf(acc[j][2]); o.w = f2bf(acc[j][3]);
            *(us4*)(yn + 16 * j + 4 * h) = o;
        }
    }
}

// ---------------- partition: edges -> 256-row buckets ----------------
// Per 4096-edge chunk: LDS histogram, one global atomicAdd per bucket to
// reserve a contiguous run in es0, LDS-cursor packed 8B scatter.
// Packed: .x = ev bits, .y = col | (row&255)<<20.
__global__ __launch_bounds__(256) void partition_edges(const float* __restrict__ ev,
                                                       const int* __restrict__ row,
                                                       const int* __restrict__ col,
                                                       int* __restrict__ bucketCnt,
                                                       uint2* __restrict__ es0,
                                                       int* __restrict__ ovfCnt,
                                                       int* __restrict__ ovfRow,
                                                       int* __restrict__ ovfCol,
                                                       float* __restrict__ ovfVal) {
    __shared__ int hist[NB];
    __shared__ int cur[NB];
    const int tid = threadIdx.x;
    const int base = blockIdx.x * CHUNK;

    for (int t = tid; t < NB; t += 256) hist[t] = 0;
    __syncthreads();

    #pragma unroll
    for (int it = 0; it < CHUNK / 256; ++it) {
        int i = base + it * 256 + tid;
        if (i < N_EDGES) atomicAdd(&hist[row[i] >> 8], 1);
    }
    __syncthreads();

    for (int t = tid; t < NB; t += 256) {
        int h = hist[t];
        int start = (h > 0) ? atomicAdd(&bucketCnt[t], h) : 0;
        cur[t] = t * BCAP + start;
    }
    __syncthreads();

    #pragma unroll
    for (int it = 0; it < CHUNK / 256; ++it) {
        int i = base + it * 256 + tid;
        if (i < N_EDGES) {
            int r = row[i];
            int b = r >> 8;
            int p = atomicAdd(&cur[b], 1);
            if (p < (b + 1) * BCAP) {
                uint2 e;
                e.x = __float_as_uint(ev[i]);
                e.y = (uint)col[i] | ((uint)(r & 255) << 20);
                es0[p] = e;
            } else {
                int q = atomicAdd(ovfCnt, 1);
                if (q < OVF_CAP) {
                    ovfRow[q] = r;
                    ovfCol[q] = col[i];
                    ovfVal[q] = ev[i];
                }
            }
        }
    }
}

// ---------------- build ELL in LDS (padded rows), write coalesced ---------
#define ELL_P 17   // padded row stride in float2 (breaks slot-p bank lock)
__global__ __launch_bounds__(256) void build_ell(const uint2* __restrict__ es0,
                                                 const int* __restrict__ bucketCnt,
                                                 float2* __restrict__ es,
                                                 int* __restrict__ counts,
                                                 int* __restrict__ ovfCnt,
                                                 int* __restrict__ ovfRow,
                                                 int* __restrict__ ovfCol,
                                                 float* __restrict__ ovfVal) {
    __shared__ float2 ell[256 * ELL_P];   // ~34KB
    __shared__ int lcnt[256];
    const int tid = threadIdx.x;
    const int b = blockIdx.x;

    lcnt[tid] = 0;
    __syncthreads();

    int cnt = bucketCnt[b];
    if (cnt > BCAP) cnt = BCAP;
    const uint2* src = es0 + (size_t)b * BCAP;

    for (int i = tid; i < cnt; i += 256) {
        uint2 e = src[i];
        int r = e.y >> 20;
        int p = atomicAdd(&lcnt[r], 1);
        if (p < ELL_K) {
            float2 rec;
            rec.x = __uint_as_float(e.x);
            rec.y = __uint_as_float(e.y & 0xFFFFFu);
            ell[r * ELL_P + p] = rec;
        } else {
            int q = atomicAdd(ovfCnt, 1);
            if (q < OVF_CAP) {
                ovfRow[q] = b * 256 + r;
                ovfCol[q] = (int)(e.y & 0xFFFFFu);
                ovfVal[q] = __uint_as_float(e.x);
            }
        }
    }
    __syncthreads();

    const int nbase = b * 256;
    int nvalid = N_NODES - nbase;
    if (nvalid > 256) nvalid = 256;

    if (tid < nvalid) counts[nbase + tid] = lcnt[tid];

    float2* dst2 = es + (size_t)nbase * ELL_K;
    for (int t = tid; t < nvalid * ELL_K; t += 256) {
        int r = t >> 4, s = t & 15;
        dst2[t] = ell[r * ELL_P + s];
    }
}

// -------- SpMM: 16 lanes/node, 2 nodes in flight per lane-group -----------
// Wave handles 8 nodes (4 groups x 2 pipelined). Loads issued for both nodes
// before FMAs wait -> 8 y-row uint4 gathers in flight.
__global__ __launch_bounds__(256) void spmm_ell(const ushort* __restrict__ y,
                                                const float2* __restrict__ es,
                                                const int* __restrict__ counts,
                                                const float* __restrict__ bias,
                                                float* __restrict__ out) {
    const int tid = threadIdx.x;
    const int lane = tid & 63;
    const int c16 = lane & 15;       // channel group: ch c16*8 .. c16*8+7
    const int sub = lane >> 4;       // node sub-index 0..3
    const int wid = blockIdx.x * 4 + (tid >> 6);

    const float4 b0 = *(const float4*)(bias + c16 * 8);
    const float4 b1 = *(const float4*)(bias + c16 * 8 + 4);

    const int nA = wid * 8 + sub;
    const int nB = nA + 4;
    int degA = counts[nA]; if (degA > ELL_K) degA = ELL_K;
    int degB = counts[nB]; if (degB > ELL_K) degB = ELL_K;
    const float4* erA = (const float4*)(es + (size_t)nA * ELL_K);
    const float4* erB = (const float4*)(es + (size_t)nB * ELL_K);

    float aA[8] = {0.f, 0.f, 0.f, 0.f, 0.f, 0.f, 0.f, 0.f};
    float aB[8] = {0.f, 0.f, 0.f, 0.f, 0.f, 0.f, 0.f, 0.f};

    #pragma unroll
    for (int g = 0; g < 4; ++g) {
        const bool pA = 4 * g < degA;
        const bool pB = 4 * g < degB;
        float4 sA0, sA1, sB0, sB1;
        uint4 uA0, uA1, uA2, uA3, uB0, uB1, uB2, uB3;
        float vA0, vA1, vA2, vA3, vB0, vB1, vB2, vB3;

        if (pA) { sA0 = erA[2 * g]; sA1 = erA[2 * g + 1]; }
        if (pB) { sB0 = erB[2 * g]; sB1 = erB[2 * g + 1]; }

        if (pA) {
            int c0 = __float_as_int(sA0.y);
            int c1 = (4 * g + 1 < degA) ? __float_as_int(sA0.w) : c0;
            int c2 = (4 * g + 2 < degA) ? __float_as_int(sA1.y) : c0;
            int c3 = (4 * g + 3 < degA) ? __float_as_int(sA1.w) : c0;
            uA0 = *(const uint4*)(y + ((size_t)c0 << 7) + c16 * 8);
            uA1 = *(const uint4*)(y + ((size_t)c1 << 7) + c16 * 8);
            uA2 = *(const uint4*)(y + ((size_t)c2 << 7) + c16 * 8);
            uA3 = *(const uint4*)(y + ((size_t)c3 << 7) + c16 * 8);
            vA0 = sA0.x;
            vA1 = (4 * g + 1 < degA) ? sA0.z : 0.f;
            vA2 = (4 * g + 2 < degA) ? sA1.x : 0.f;
            vA3 = (4 * g + 3 < degA) ? sA1.z : 0.f;
        }
        if (pB) {
            int c0 = __float_as_int(sB0.y);
            int c1 = (4 * g + 1 < degB) ? __float_as_int(sB0.w) : c0;
            int c2 = (4 * g + 2 < degB) ? __float_as_int(sB1.y) : c0;
            int c3 = (4 * g + 3 < degB) ? __float_as_int(sB1.w) : c0;
            uB0 = *(const uint4*)(y + ((size_t)c0 << 7) + c16 * 8);
            uB1 = *(const uint4*)(y + ((size_t)c1 << 7) + c16 * 8);
            uB2 = *(const uint4*)(y + ((size_t)c2 << 7) + c16 * 8);
            uB3 = *(const uint4*)(y + ((size_t)c3 << 7) + c16 * 8);
            vB0 = sB0.x;
            vB1 = (4 * g + 1 < degB) ? sB0.z : 0.f;
            vB2 = (4 * g + 2 < degB) ? sB1.x : 0.f;
            vB3 = (4 * g + 3 < degB) ? sB1.z : 0.f;
        }

        if (pA) {
            aA[0] += vA0 * bflo(uA0.x); aA[1] += vA0 * bfhi(uA0.x);
            aA[2] += vA0 * bflo(uA0.y); aA[3] += vA0 * bfhi(uA0.y);
            aA[4] += vA0 * bflo(uA0.z); aA[5] += vA0 * bfhi(uA0.z);
            aA[6] += vA0 * bflo(uA0.w); aA[7] += vA0 * bfhi(uA0.w);
            aA[0] += vA1 * bflo(uA1.x); aA[1] += vA1 * bfhi(uA1.x);
            aA[2] += vA1 * bflo(uA1.y); aA[3] += vA1 * bfhi(uA1.y);
            aA[4] += vA1 * bflo(uA1.z); aA[5] += vA1 * bfhi(uA1.z);
            aA[6] += vA1 * bflo(uA1.w); aA[7] += vA1 * bfhi(uA1.w);
            aA[0] += vA2 * bflo(uA2.x); aA[1] += vA2 * bfhi(uA2.x);
            aA[2] += vA2 * bflo(uA2.y); aA[3] += vA2 * bfhi(uA2.y);
            aA[4] += vA2 * bflo(uA2.z); aA[5] += vA2 * bfhi(uA2.z);
            aA[6] += vA2 * bflo(uA2.w); aA[7] += vA2 * bfhi(uA2.w);
            aA[0] += vA3 * bflo(uA3.x); aA[1] += vA3 * bfhi(uA3.x);
            aA[2] += vA3 * bflo(uA3.y); aA[3] += vA3 * bfhi(uA3.y);
            aA[4] += vA3 * bflo(uA3.z); aA[5] += vA3 * bfhi(uA3.z);
            aA[6] += vA3 * bflo(uA3.w); aA[7] += vA3 * bfhi(uA3.w);
        }
        if (pB) {
            aB[0] += vB0 * bflo(uB0.x); aB[1] += vB0 * bfhi(uB0.x);
            aB[2] += vB0 * bflo(uB0.y); aB[3] += vB0 * bfhi(uB0.y);
            aB[4] += vB0 * bflo(uB0.z); aB[5] += vB0 * bfhi(uB0.z);
            aB[6] += vB0 * bflo(uB0.w); aB[7] += vB0 * bfhi(uB0.w);
            aB[0] += vB1 * bflo(uB1.x); aB[1] += vB1 * bfhi(uB1.x);
            aB[2] += vB1 * bflo(uB1.y); aB[3] += vB1 * bfhi(uB1.y);
            aB[4] += vB1 * bflo(uB1.z); aB[5] += vB1 * bfhi(uB1.z);
            aB[6] += vB1 * bflo(uB1.w); aB[7] += vB1 * bfhi(uB1.w);
            aB[0] += vB2 * bflo(uB2.x); aB[1] += vB2 * bfhi(uB2.x);
            aB[2] += vB2 * bflo(uB2.y); aB[3] += vB2 * bfhi(uB2.y);
            aB[4] += vB2 * bflo(uB2.z); aB[5] += vB2 * bfhi(uB2.z);
            aB[6] += vB2 * bflo(uB2.w); aB[7] += vB2 * bfhi(uB2.w);
            aB[0] += vB3 * bflo(uB3.x); aB[1] += vB3 * bfhi(uB3.x);
            aB[2] += vB3 * bflo(uB3.y); aB[3] += vB3 * bfhi(uB3.y);
            aB[4] += vB3 * bflo(uB3.z); aB[5] += vB3 * bfhi(uB3.z);
            aB[6] += vB3 * bflo(uB3.w); aB[7] += vB3 * bfhi(uB3.w);
        }
    }

    float4 oA0 = {aA[0] + b0.x, aA[1] + b0.y, aA[2] + b0.z, aA[3] + b0.w};
    float4 oA1 = {aA[4] + b1.x, aA[5] + b1.y, aA[6] + b1.z, aA[7] + b1.w};
    float* orA = out + ((size_t)nA << 7) + c16 * 8;
    *(float4*)orA = oA0;
    *(float4*)(orA + 4) = oA1;

    float4 oB0 = {aB[0] + b0.x, aB[1] + b0.y, aB[2] + b0.z, aB[3] + b0.w};
    float4 oB1 = {aB[4] + b1.x, aB[5] + b1.y, aB[6] + b1.z, aB[7] + b1.w};
    float* orB = out + ((size_t)nB << 7) + c16 * 8;
    *(float4*)orB = oB0;
    *(float4*)(orB + 4) = oB1;
}

// ---------------- overflow fixup (rare) ----------------
__global__ void ovf_fix(const ushort* __restrict__ y, const int* __restrict__ ovfRow,
                        const int* __restrict__ ovfCol, const float* __restrict__ ovfVal,
                        const int* __restrict__ ovfCnt, float* __restrict__ out) {
    int nOvf = *ovfCnt;
    if (nOvf > OVF_CAP) nOvf = OVF_CAP;
    int total = nOvf * 32;
    for (int idx = blockIdx.x * 256 + threadIdx.x; idx < total; idx += gridDim.x * 256) {
        int e = idx >> 5;
        int c = idx & 31;
        int r = ovfRow[e];
        int col = ovfCol[e];
        float v = ovfVal[e];
        uint2 u = *(const uint2*)(y + ((size_t)col << 7) + c * 4);
        atomicAdd(&out[(size_t)r * D + c * 4 + 0], v * bflo(u.x));
        atomicAdd(&out[(size_t)r * D + c * 4 + 1], v * bfhi(u.x));
        atomicAdd(&out[(size_t)r * D + c * 4 + 2], v * bflo(u.y));
        atomicAdd(&out[(size_t)r * D + c * 4 + 3], v * bfhi(u.y));
    }
}

// ---------------- launch ----------------
extern "C" void kernel_launch(void* const* d_in, const int* in_sizes, int n_in,
                              void* d_out, int out_size, void* d_ws, size_t ws_size,
                              hipStream_t stream) {
    const float* x = (const float*)d_in[0];
    const float* w = (const float*)d_in[1];
    const float* bias = (const float*)d_in[2];
    const float* ev = (const float*)d_in[3];
    const int* row = (const int*)d_in[4];
    const int* col = (const int*)d_in[5];
    float* out = (float*)d_out;

    size_t off = 0;
    auto carve = [&](size_t bytes) -> void* {
        void* p = (char*)d_ws + off;
        off += (bytes + 255) & ~(size_t)255;
        return p;
    };
    ushort* y = (ushort*)carve((size_t)N_NODES * D * sizeof(ushort));
    int* counts = (int*)carve((size_t)N_NODES * sizeof(int));
    float2* es = (float2*)carve((size_t)N_NODES * ELL_K * sizeof(float2));
    uint2* es0 = (uint2*)carve((size_t)NB * BCAP * sizeof(uint2));
    int* bucketCnt = (int*)carve((NB + 1) * sizeof(int));  // [NB] = ovfCnt
    int* ovfCnt = bucketCnt + NB;
    int* ovfRow = (int*)carve(OVF_CAP * sizeof(int));
    int* ovfCol = (int*)carve(OVF_CAP * sizeof(int));
    float* ovfVal = (float*)carve(OVF_CAP * sizeof(float));

    gemm_xw<<<512, 256, 0, stream>>>(x, w, y, bucketCnt);
    partition_edges<<<NCHUNKS, 256, 0, stream>>>(ev, row, col, bucketCnt, es0,
                                                 ovfCnt, ovfRow, ovfCol, ovfVal);
    build_ell<<<NB, 256, 0, stream>>>(es0, bucketCnt, es, counts,
                                      ovfCnt, ovfRow, ovfCol, ovfVal);
    spmm_ell<<<N_NODES / 32, 256, 0, stream>>>(y, es, counts, bias, out);
    ovf_fix<<<16, 256, 0, stream>>>(y, ovfRow, ovfCol, ovfVal, ovfCnt, out);
}

// Round 7
// 88.214 us; speedup vs baseline: 1.0202x; 1.0202x over previous
//
#include <hip/hip_runtime.h>
#include <hip/hip_bf16.h>

// GCN layer: out = segment_sum(edge_val * (x@W)[col], row) + bias
// N=100000 nodes, E=640000 edges, D=128.
// y bf16. Pipeline: gemm (MFMA, LDS-resident W, 4 blk/CU; inits cursors) ->
// edge partition (256-row buckets) -> LDS-built zero-padded ELL ->
// branch-free spmm (1 node / 16-lane group) -> overflow fixup.

#define N_NODES 100000
#define N_EDGES 640000
#define D 128
#define ELL_K 16
#define OVF_CAP 8192
#define NB 391          // ceil(N_NODES/256) row buckets
#define BCAP 2048       // per-bucket edge capacity (avg 1638)
#define CHUNK 2048
#define NCHUNKS 313     // ceil(N_EDGES/CHUNK)
#define N_TILES 6250
#define ELL_P 17        // padded LDS row stride (float2 units)

typedef __attribute__((ext_vector_type(8))) short short8;
typedef __attribute__((ext_vector_type(4))) float f32x4;
typedef __attribute__((ext_vector_type(4))) ushort us4;

__device__ __forceinline__ ushort f2bf(float f) {
    uint u = __float_as_uint(f);
    u += 0x7fff + ((u >> 16) & 1);   // RNE
    return (ushort)(u >> 16);
}
__device__ __forceinline__ float bflo(uint u) { return __uint_as_float(u << 16); }
__device__ __forceinline__ float bfhi(uint u) { return __uint_as_float(u & 0xffff0000u); }

// ---------------- GEMM: y(bf16) = x @ W via MFMA 16x16x32 ----------------
// W^T staged once in LDS (XOR-swizzled). B-fragments are read from LDS at
// each MFMA (memory clobber stops LICM from hoisting 128 VGPRs of B), so
// VGPR stays ~100 -> 4 blocks/CU, 16 waves/CU for latency hiding.
// Swapped-operand mfma: each lane owns one node-row -> ushort4 stores.
__global__ __launch_bounds__(256, 4) void gemm_xw(const float* __restrict__ x,
                                                  const float* __restrict__ w,
                                                  ushort* __restrict__ y,
                                                  int* __restrict__ bucketCnt) {
    __shared__ ushort wt[128 * 128];  // 32KB; idx = n*128 + (k ^ ((n&7)<<3))
    const int tid = threadIdx.x;

    int gz = blockIdx.x * 256 + tid;
    if (gz <= NB) bucketCnt[gz] = 0;   // [NB] doubles as ovfCnt

    #pragma unroll
    for (int it = 0; it < 16; ++it) {
        int idx4 = tid + it * 256;        // 4096 float4 = 128x128
        int k = idx4 >> 5;
        int n0 = (idx4 & 31) * 4;
        float4 v = *(const float4*)(w + (size_t)idx4 * 4);
        float vv[4] = {v.x, v.y, v.z, v.w};
        #pragma unroll
        for (int q = 0; q < 4; ++q) {
            int n = n0 + q;
            wt[n * 128 + (k ^ ((n & 7) << 3))] = f2bf(vv[q]);
        }
    }
    __syncthreads();

    const int lane = tid & 63;
    const int l15 = lane & 15;
    const int h = lane >> 4;

    const int waveGlobal = blockIdx.x * 4 + (tid >> 6);
    const int nWaves = gridDim.x * 4;   // 3128

    for (int t = waveGlobal; t < N_TILES; t += nWaves) {
        asm volatile("" ::: "memory");   // keep B-frag LDS reads inside loop
        const float* xr = x + (size_t)(t * 16 + l15) * D;
        float4 xb[8];
        #pragma unroll
        for (int ks = 0; ks < 4; ++ks) {
            xb[2 * ks]     = *(const float4*)(xr + 32 * ks + 8 * h);
            xb[2 * ks + 1] = *(const float4*)(xr + 32 * ks + 8 * h + 4);
        }
        short8 a[4];
        #pragma unroll
        for (int ks = 0; ks < 4; ++ks) {
            const float* p0 = (const float*)&xb[2 * ks];
            const float* p1 = (const float*)&xb[2 * ks + 1];
            a[ks][0] = f2bf(p0[0]); a[ks][1] = f2bf(p0[1]);
            a[ks][2] = f2bf(p0[2]); a[ks][3] = f2bf(p0[3]);
            a[ks][4] = f2bf(p1[0]); a[ks][5] = f2bf(p1[1]);
            a[ks][6] = f2bf(p1[2]); a[ks][7] = f2bf(p1[3]);
        }
        f32x4 acc[8];
        #pragma unroll
        for (int j = 0; j < 8; ++j) acc[j] = (f32x4){0.f, 0.f, 0.f, 0.f};
        #pragma unroll
        for (int ks = 0; ks < 4; ++ks) {
            const int k0 = 32 * ks + 8 * h;
            #pragma unroll
            for (int j = 0; j < 8; ++j) {
                int n = 16 * j + l15;
                short8 b = *(const short8*)&wt[n * 128 + (k0 ^ ((n & 7) << 3))];
                acc[j] = __builtin_amdgcn_mfma_f32_16x16x32_bf16(b, a[ks], acc[j], 0, 0, 0);
            }
        }
        // node = t*16 + l15, channel = 16j + 4h + r
        ushort* yn = y + (size_t)(t * 16 + l15) * D;
        #pragma unroll
        for (int j = 0; j < 8; ++j) {
            us4 o;
            o.x = f2bf(acc[j][0]); o.y = f2bf(acc[j][1]);
            o.z = f2bf(acc[j][2]); o.w = f2bf(acc[j][3]);
            *(us4*)(yn + 16 * j + 4 * h) = o;
        }
    }
}

// ---------------- partition: edges -> 256-row buckets ----------------
// Per 2048-edge chunk: LDS histogram, one global atomicAdd per bucket to
// reserve a contiguous run in es0, LDS-cursor packed 8B scatter.
// Packed: .x = ev bits, .y = col | (row&255)<<20.
__global__ __launch_bounds__(256) void partition_edges(const float* __restrict__ ev,
                                                       const int* __restrict__ row,
                                                       const int* __restrict__ col,
                                                       int* __restrict__ bucketCnt,
                                                       uint2* __restrict__ es0,
                                                       int* __restrict__ ovfCnt,
                                                       int* __restrict__ ovfRow,
                                                       int* __restrict__ ovfCol,
                                                       float* __restrict__ ovfVal) {
    __shared__ int hist[NB];
    __shared__ int cur[NB];
    const int tid = threadIdx.x;
    const int base = blockIdx.x * CHUNK;

    for (int t = tid; t < NB; t += 256) hist[t] = 0;
    __syncthreads();

    #pragma unroll
    for (int it = 0; it < CHUNK / 256; ++it) {
        int i = base + it * 256 + tid;
        if (i < N_EDGES) atomicAdd(&hist[row[i] >> 8], 1);
    }
    __syncthreads();

    for (int t = tid; t < NB; t += 256) {
        int h = hist[t];
        int start = (h > 0) ? atomicAdd(&bucketCnt[t], h) : 0;
        cur[t] = t * BCAP + start;
    }
    __syncthreads();

    #pragma unroll
    for (int it = 0; it < CHUNK / 256; ++it) {
        int i = base + it * 256 + tid;
        if (i < N_EDGES) {
            int r = row[i];
            int b = r >> 8;
            int p = atomicAdd(&cur[b], 1);
            if (p < (b + 1) * BCAP) {
                uint2 e;
                e.x = __float_as_uint(ev[i]);
                e.y = (uint)col[i] | ((uint)(r & 255) << 20);
                es0[p] = e;
            } else {
                int q = atomicAdd(ovfCnt, 1);
                if (q < OVF_CAP) {
                    ovfRow[q] = r;
                    ovfCol[q] = col[i];
                    ovfVal[q] = ev[i];
                }
            }
        }
    }
}

// ------- build ELL in LDS (zero-padded to 16 slots), write coalesced ------
// Dummy slots get (v=0, col=0): spmm reads y-row 0 (cache-hot) * 0.0.
__global__ __launch_bounds__(256) void build_ell(const uint2* __restrict__ es0,
                                                 const int* __restrict__ bucketCnt,
                                                 float2* __restrict__ es,
                                                 int* __restrict__ ovfCnt,
                                                 int* __restrict__ ovfRow,
                                                 int* __restrict__ ovfCol,
                                                 float* __restrict__ ovfVal) {
    __shared__ float2 ell[256 * ELL_P];   // ~34KB
    __shared__ int lcnt[256];
    const int tid = threadIdx.x;
    const int b = blockIdx.x;

    lcnt[tid] = 0;
    #pragma unroll
    for (int it = 0; it < ELL_P; ++it)
        ell[it * 256 + tid] = (float2){0.f, 0.f};
    __syncthreads();

    int cnt = bucketCnt[b];
    if (cnt > BCAP) cnt = BCAP;
    const uint2* src = es0 + (size_t)b * BCAP;

    for (int i = tid; i < cnt; i += 256) {
        uint2 e = src[i];
        int r = e.y >> 20;
        int p = atomicAdd(&lcnt[r], 1);
        if (p < ELL_K) {
            float2 rec;
            rec.x = __uint_as_float(e.x);
            rec.y = __uint_as_float(e.y & 0xFFFFFu);
            ell[r * ELL_P + p] = rec;
        } else {
            int q = atomicAdd(ovfCnt, 1);
            if (q < OVF_CAP) {
                ovfRow[q] = b * 256 + r;
                ovfCol[q] = (int)(e.y & 0xFFFFFu);
                ovfVal[q] = __uint_as_float(e.x);
            }
        }
    }
    __syncthreads();

    const int nbase = b * 256;
    int nvalid = N_NODES - nbase;
    if (nvalid > 256) nvalid = 256;

    float2* dst2 = es + (size_t)nbase * ELL_K;
    for (int t = tid; t < nvalid * ELL_K; t += 256) {
        int r = t >> 4, s = t & 15;
        dst2[t] = ell[r * ELL_P + s];
    }
}

// -------- SpMM: branch-free, 1 node per 16-lane group, 16 fixed slots -----
__global__ __launch_bounds__(256) void spmm_ell(const ushort* __restrict__ y,
                                                const float2* __restrict__ es,
                                                const float* __restrict__ bias,
                                                float* __restrict__ out) {
    const int tid = threadIdx.x;
    const int c16 = tid & 15;
    const int n = blockIdx.x * 16 + (tid >> 4);

    const float4* er = (const float4*)(es + (size_t)n * ELL_K);  // 8 float4
    float4 e0 = er[0], e1 = er[1], e2 = er[2], e3 = er[3];
    float4 e4 = er[4], e5 = er[5], e6 = er[6], e7 = er[7];

    const ushort* yb = y + c16 * 8;
    #define YLD(c) (*(const uint4*)(yb + ((size_t)__float_as_int(c) << 7)))
    uint4 u0 = YLD(e0.y), u1 = YLD(e0.w), u2 = YLD(e1.y), u3 = YLD(e1.w);
    uint4 u4 = YLD(e2.y), u5 = YLD(e2.w), u6 = YLD(e3.y), u7 = YLD(e3.w);
    uint4 u8 = YLD(e4.y), u9 = YLD(e4.w), uA = YLD(e5.y), uB = YLD(e5.w);
    uint4 uC = YLD(e6.y), uD = YLD(e6.w), uE = YLD(e7.y), uF = YLD(e7.w);
    #undef YLD

    float a[8] = {0.f, 0.f, 0.f, 0.f, 0.f, 0.f, 0.f, 0.f};
    #define FMA8(v, u) do { \
        a[0] += (v) * bflo((u).x); a[1] += (v) * bfhi((u).x); \
        a[2] += (v) * bflo((u).y); a[3] += (v) * bfhi((u).y); \
        a[4] += (v) * bflo((u).z); a[5] += (v) * bfhi((u).z); \
        a[6] += (v) * bflo((u).w); a[7] += (v) * bfhi((u).w); } while (0)
    FMA8(e0.x, u0); FMA8(e0.z, u1); FMA8(e1.x, u2); FMA8(e1.z, u3);
    FMA8(e2.x, u4); FMA8(e2.z, u5); FMA8(e3.x, u6); FMA8(e3.z, u7);
    FMA8(e4.x, u8); FMA8(e4.z, u9); FMA8(e5.x, uA); FMA8(e5.z, uB);
    FMA8(e6.x, uC); FMA8(e6.z, uD); FMA8(e7.x, uE); FMA8(e7.z, uF);
    #undef FMA8

    const float4 b0 = *(const float4*)(bias + c16 * 8);
    const float4 b1 = *(const float4*)(bias + c16 * 8 + 4);
    float4 o0 = {a[0] + b0.x, a[1] + b0.y, a[2] + b0.z, a[3] + b0.w};
    float4 o1 = {a[4] + b1.x, a[5] + b1.y, a[6] + b1.z, a[7] + b1.w};
    float* orow = out + ((size_t)n << 7) + c16 * 8;
    *(float4*)orow = o0;
    *(float4*)(orow + 4) = o1;
}

// ---------------- overflow fixup (rare) ----------------
__global__ void ovf_fix(const ushort* __restrict__ y, const int* __restrict__ ovfRow,
                        const int* __restrict__ ovfCol, const float* __restrict__ ovfVal,
                        const int* __restrict__ ovfCnt, float* __restrict__ out) {
    int nOvf = *ovfCnt;
    if (nOvf > OVF_CAP) nOvf = OVF_CAP;
    int total = nOvf * 32;
    for (int idx = blockIdx.x * 256 + threadIdx.x; idx < total; idx += gridDim.x * 256) {
        int e = idx >> 5;
        int c = idx & 31;
        int r = ovfRow[e];
        int col = ovfCol[e];
        float v = ovfVal[e];
        uint2 u = *(const uint2*)(y + ((size_t)col << 7) + c * 4);
        atomicAdd(&out[(size_t)r * D + c * 4 + 0], v * bflo(u.x));
        atomicAdd(&out[(size_t)r * D + c * 4 + 1], v * bfhi(u.x));
        atomicAdd(&out[(size_t)r * D + c * 4 + 2], v * bflo(u.y));
        atomicAdd(&out[(size_t)r * D + c * 4 + 3], v * bfhi(u.y));
    }
}

// ---------------- launch ----------------
extern "C" void kernel_launch(void* const* d_in, const int* in_sizes, int n_in,
                              void* d_out, int out_size, void* d_ws, size_t ws_size,
                              hipStream_t stream) {
    const float* x = (const float*)d_in[0];
    const float* w = (const float*)d_in[1];
    const float* bias = (const float*)d_in[2];
    const float* ev = (const float*)d_in[3];
    const int* row = (const int*)d_in[4];
    const int* col = (const int*)d_in[5];
    float* out = (float*)d_out;

    size_t off = 0;
    auto carve = [&](size_t bytes) -> void* {
        void* p = (char*)d_ws + off;
        off += (bytes + 255) & ~(size_t)255;
        return p;
    };
    ushort* y = (ushort*)carve((size_t)N_NODES * D * sizeof(ushort));
    float2* es = (float2*)carve((size_t)N_NODES * ELL_K * sizeof(float2));
    uint2* es0 = (uint2*)carve((size_t)NB * BCAP * sizeof(uint2));
    int* bucketCnt = (int*)carve((NB + 1) * sizeof(int));  // [NB] = ovfCnt
    int* ovfCnt = bucketCnt + NB;
    int* ovfRow = (int*)carve(OVF_CAP * sizeof(int));
    int* ovfCol = (int*)carve(OVF_CAP * sizeof(int));
    float* ovfVal = (float*)carve(OVF_CAP * sizeof(float));

    gemm_xw<<<782, 256, 0, stream>>>(x, w, y, bucketCnt);
    partition_edges<<<NCHUNKS, 256, 0, stream>>>(ev, row, col, bucketCnt, es0,
                                                 ovfCnt, ovfRow, ovfCol, ovfVal);
    build_ell<<<NB, 256, 0, stream>>>(es0, bucketCnt, es,
                                      ovfCnt, ovfRow, ovfCol, ovfVal);
    spmm_ell<<<N_NODES / 16, 256, 0, stream>>>(y, es, bias, out);
    ovf_fix<<<16, 256, 0, stream>>>(y, ovfRow, ovfCol, ovfVal, ovfCnt, out);
}

// Round 8
// 87.338 us; speedup vs baseline: 1.0304x; 1.0100x over previous
//
#include <hip/hip_runtime.h>
#include <hip/hip_bf16.h>

// GCN layer: out = segment_sum(edge_val * (x@W)[col], row) + bias
// N=100000 nodes, E=640000 edges, D=128.
// y bf16. Pipeline: gemm (MFMA, LDS-resident W; inits cursors) ->
// edge partition (256-row buckets, es0) -> fused {LDS ELL build + branch-free
// spmm} per 64-row slice -> overflow fixup.

#define N_NODES 100000
#define N_EDGES 640000
#define D 128
#define ELL_K 16
#define OVF_CAP 8192
#define NB 391          // ceil(N_NODES/256) row buckets
#define BCAP 2048       // per-bucket edge capacity (avg 1638)
#define CHUNK 4096
#define NCHUNKS 157     // ceil(N_EDGES/CHUNK)
#define N_TILES 6250
#define ELL_P 18        // LDS row stride (float2 units): even -> b128 aligned
#define NSLICE 1564     // NB*4 slices of 64 rows

typedef __attribute__((ext_vector_type(8))) short short8;
typedef __attribute__((ext_vector_type(4))) float f32x4;
typedef __attribute__((ext_vector_type(4))) ushort us4;

__device__ __forceinline__ ushort f2bf(float f) {
    uint u = __float_as_uint(f);
    u += 0x7fff + ((u >> 16) & 1);   // RNE
    return (ushort)(u >> 16);
}
__device__ __forceinline__ float bflo(uint u) { return __uint_as_float(u << 16); }
__device__ __forceinline__ float bfhi(uint u) { return __uint_as_float(u & 0xffff0000u); }

// ---------------- GEMM: y(bf16) = x @ W via MFMA 16x16x32 ----------------
// W^T staged once in LDS (XOR-swizzled). B-fragments re-read from LDS at each
// MFMA (memory clobber stops LICM hoisting) -> ~100 VGPR -> 4 blocks/CU.
// Swapped-operand mfma: each lane owns one node-row -> ushort4 stores.
__global__ __launch_bounds__(256, 4) void gemm_xw(const float* __restrict__ x,
                                                  const float* __restrict__ w,
                                                  ushort* __restrict__ y,
                                                  int* __restrict__ bucketCnt) {
    __shared__ ushort wt[128 * 128];  // 32KB; idx = n*128 + (k ^ ((n&7)<<3))
    const int tid = threadIdx.x;

    int gz = blockIdx.x * 256 + tid;
    if (gz <= NB) bucketCnt[gz] = 0;   // [NB] doubles as ovfCnt

    #pragma unroll
    for (int it = 0; it < 16; ++it) {
        int idx4 = tid + it * 256;        // 4096 float4 = 128x128
        int k = idx4 >> 5;
        int n0 = (idx4 & 31) * 4;
        float4 v = *(const float4*)(w + (size_t)idx4 * 4);
        float vv[4] = {v.x, v.y, v.z, v.w};
        #pragma unroll
        for (int q = 0; q < 4; ++q) {
            int n = n0 + q;
            wt[n * 128 + (k ^ ((n & 7) << 3))] = f2bf(vv[q]);
        }
    }
    __syncthreads();

    const int lane = tid & 63;
    const int l15 = lane & 15;
    const int h = lane >> 4;

    const int waveGlobal = blockIdx.x * 4 + (tid >> 6);
    const int nWaves = gridDim.x * 4;   // 3128

    for (int t = waveGlobal; t < N_TILES; t += nWaves) {
        asm volatile("" ::: "memory");   // keep B-frag LDS reads inside loop
        const float* xr = x + (size_t)(t * 16 + l15) * D;
        float4 xb[8];
        #pragma unroll
        for (int ks = 0; ks < 4; ++ks) {
            xb[2 * ks]     = *(const float4*)(xr + 32 * ks + 8 * h);
            xb[2 * ks + 1] = *(const float4*)(xr + 32 * ks + 8 * h + 4);
        }
        short8 a[4];
        #pragma unroll
        for (int ks = 0; ks < 4; ++ks) {
            const float* p0 = (const float*)&xb[2 * ks];
            const float* p1 = (const float*)&xb[2 * ks + 1];
            a[ks][0] = f2bf(p0[0]); a[ks][1] = f2bf(p0[1]);
            a[ks][2] = f2bf(p0[2]); a[ks][3] = f2bf(p0[3]);
            a[ks][4] = f2bf(p1[0]); a[ks][5] = f2bf(p1[1]);
            a[ks][6] = f2bf(p1[2]); a[ks][7] = f2bf(p1[3]);
        }
        f32x4 acc[8];
        #pragma unroll
        for (int j = 0; j < 8; ++j) acc[j] = (f32x4){0.f, 0.f, 0.f, 0.f};
        #pragma unroll
        for (int ks = 0; ks < 4; ++ks) {
            const int k0 = 32 * ks + 8 * h;
            #pragma unroll
            for (int j = 0; j < 8; ++j) {
                int n = 16 * j + l15;
                short8 b = *(const short8*)&wt[n * 128 + (k0 ^ ((n & 7) << 3))];
                acc[j] = __builtin_amdgcn_mfma_f32_16x16x32_bf16(b, a[ks], acc[j], 0, 0, 0);
            }
        }
        // node = t*16 + l15, channel = 16j + 4h + r
        ushort* yn = y + (size_t)(t * 16 + l15) * D;
        #pragma unroll
        for (int j = 0; j < 8; ++j) {
            us4 o;
            o.x = f2bf(acc[j][0]); o.y = f2bf(acc[j][1]);
            o.z = f2bf(acc[j][2]); o.w = f2bf(acc[j][3]);
            *(us4*)(yn + 16 * j + 4 * h) = o;
        }
    }
}

// ---------------- partition: edges -> 256-row buckets ----------------
// Per 4096-edge chunk: LDS histogram, one global atomicAdd per bucket to
// reserve a contiguous run in es0, LDS-cursor packed 8B scatter.
// Packed: .x = ev bits, .y = col | (row&255)<<20.
__global__ __launch_bounds__(256) void partition_edges(const float* __restrict__ ev,
                                                       const int* __restrict__ row,
                                                       const int* __restrict__ col,
                                                       int* __restrict__ bucketCnt,
                                                       uint2* __restrict__ es0,
                                                       int* __restrict__ ovfCnt,
                                                       int* __restrict__ ovfRow,
                                                       int* __restrict__ ovfCol,
                                                       float* __restrict__ ovfVal) {
    __shared__ int hist[NB];
    __shared__ int cur[NB];
    const int tid = threadIdx.x;
    const int base = blockIdx.x * CHUNK;

    for (int t = tid; t < NB; t += 256) hist[t] = 0;
    __syncthreads();

    #pragma unroll
    for (int it = 0; it < CHUNK / 256; ++it) {
        int i = base + it * 256 + tid;
        if (i < N_EDGES) atomicAdd(&hist[row[i] >> 8], 1);
    }
    __syncthreads();

    for (int t = tid; t < NB; t += 256) {
        int h = hist[t];
        int start = (h > 0) ? atomicAdd(&bucketCnt[t], h) : 0;
        cur[t] = t * BCAP + start;
    }
    __syncthreads();

    #pragma unroll
    for (int it = 0; it < CHUNK / 256; ++it) {
        int i = base + it * 256 + tid;
        if (i < N_EDGES) {
            int r = row[i];
            int b = r >> 8;
            int p = atomicAdd(&cur[b], 1);
            if (p < (b + 1) * BCAP) {
                uint2 e;
                e.x = __float_as_uint(ev[i]);
                e.y = (uint)col[i] | ((uint)(r & 255) << 20);
                es0[p] = e;
            } else {
                int q = atomicAdd(ovfCnt, 1);
                if (q < OVF_CAP) {
                    ovfRow[q] = r;
                    ovfCol[q] = col[i];
                    ovfVal[q] = ev[i];
                }
            }
        }
    }
}

// ------ fused: LDS ELL build (64-row slice) + branch-free SpMM ------------
// Block = slice s of bucket b (4 slices/bucket). Phase 1: scan the bucket's
// es0 run, keep edges whose row is in this slice, LDS-atomic slot assign into
// zero-padded ELL (dummy: v=0, col=0 -> y row 0 L1-hot). Phase 2: 16 groups
// of 16 lanes; each group does 4 nodes x 16 fixed slots, uint4 y gathers.
__global__ __launch_bounds__(256) void ell_spmm(const uint2* __restrict__ es0,
                                                const int* __restrict__ bucketCnt,
                                                const ushort* __restrict__ y,
                                                const float* __restrict__ bias,
                                                float* __restrict__ out,
                                                int* __restrict__ ovfCnt,
                                                int* __restrict__ ovfRow,
                                                int* __restrict__ ovfCol,
                                                float* __restrict__ ovfVal) {
    __shared__ float2 ell[64 * ELL_P];   // 9KB
    __shared__ int lcnt[64];
    const int tid = threadIdx.x;
    const int b = blockIdx.x >> 2;
    const int slice = blockIdx.x & 3;

    if (tid < 64) lcnt[tid] = 0;
    #pragma unroll
    for (int it = 0; it < (64 * ELL_P + 255) / 256; ++it) {
        int t = it * 256 + tid;
        if (t < 64 * ELL_P) ell[t] = (float2){0.f, 0.f};
    }
    __syncthreads();

    int cnt = bucketCnt[b];
    if (cnt > BCAP) cnt = BCAP;
    const uint2* src = es0 + (size_t)b * BCAP;

    for (int i = tid; i < cnt; i += 256) {
        uint2 e = src[i];
        int r = e.y >> 20;               // 0..255 within bucket
        if ((r >> 6) == slice) {
            int rl = r & 63;
            int p = atomicAdd(&lcnt[rl], 1);
            if (p < ELL_K) {
                float2 rec;
                rec.x = __uint_as_float(e.x);
                rec.y = __uint_as_float(e.y & 0xFFFFFu);
                ell[rl * ELL_P + p] = rec;
            } else {
                int q = atomicAdd(ovfCnt, 1);
                if (q < OVF_CAP) {
                    ovfRow[q] = b * 256 + r;
                    ovfCol[q] = (int)(e.y & 0xFFFFFu);
                    ovfVal[q] = __uint_as_float(e.x);
                }
            }
        }
    }
    __syncthreads();

    // ---- phase 2: gather. group g (16 lanes) -> nodes 4g..4g+3 of slice ----
    const int c16 = tid & 15;
    const int grp = tid >> 4;            // 0..15
    const int nbase = blockIdx.x * 64;   // global node base of this slice

    const float4 b0 = *(const float4*)(bias + c16 * 8);
    const float4 b1 = *(const float4*)(bias + c16 * 8 + 4);
    const ushort* yb = y + c16 * 8;

    #pragma unroll 1
    for (int rep = 0; rep < 4; ++rep) {
        const int rl = grp * 4 + rep;    // local row 0..63
        const int n = nbase + rl;
        const float4* er = (const float4*)&ell[rl * ELL_P];  // slots 2q,2q+1
        float4 e0 = er[0], e1 = er[1], e2 = er[2], e3 = er[3];
        float4 e4 = er[4], e5 = er[5], e6 = er[6], e7 = er[7];

        #define YLD(c) (*(const uint4*)(yb + ((size_t)__float_as_int(c) << 7)))
        uint4 u0 = YLD(e0.y), u1 = YLD(e0.w), u2 = YLD(e1.y), u3 = YLD(e1.w);
        uint4 u4 = YLD(e2.y), u5 = YLD(e2.w), u6 = YLD(e3.y), u7 = YLD(e3.w);
        uint4 u8 = YLD(e4.y), u9 = YLD(e4.w), uA = YLD(e5.y), uB = YLD(e5.w);
        uint4 uC = YLD(e6.y), uD = YLD(e6.w), uE = YLD(e7.y), uF = YLD(e7.w);
        #undef YLD

        float a[8] = {0.f, 0.f, 0.f, 0.f, 0.f, 0.f, 0.f, 0.f};
        #define FMA8(v, u) do { \
            a[0] += (v) * bflo((u).x); a[1] += (v) * bfhi((u).x); \
            a[2] += (v) * bflo((u).y); a[3] += (v) * bfhi((u).y); \
            a[4] += (v) * bflo((u).z); a[5] += (v) * bfhi((u).z); \
            a[6] += (v) * bflo((u).w); a[7] += (v) * bfhi((u).w); } while (0)
        FMA8(e0.x, u0); FMA8(e0.z, u1); FMA8(e1.x, u2); FMA8(e1.z, u3);
        FMA8(e2.x, u4); FMA8(e2.z, u5); FMA8(e3.x, u6); FMA8(e3.z, u7);
        FMA8(e4.x, u8); FMA8(e4.z, u9); FMA8(e5.x, uA); FMA8(e5.z, uB);
        FMA8(e6.x, uC); FMA8(e6.z, uD); FMA8(e7.x, uE); FMA8(e7.z, uF);
        #undef FMA8

        if (n < N_NODES) {
            float4 o0 = {a[0] + b0.x, a[1] + b0.y, a[2] + b0.z, a[3] + b0.w};
            float4 o1 = {a[4] + b1.x, a[5] + b1.y, a[6] + b1.z, a[7] + b1.w};
            float* orow = out + ((size_t)n << 7) + c16 * 8;
            *(float4*)orow = o0;
            *(float4*)(orow + 4) = o1;
        }
    }
}

// ---------------- overflow fixup (rare) ----------------
__global__ void ovf_fix(const ushort* __restrict__ y, const int* __restrict__ ovfRow,
                        const int* __restrict__ ovfCol, const float* __restrict__ ovfVal,
                        const int* __restrict__ ovfCnt, float* __restrict__ out) {
    int nOvf = *ovfCnt;
    if (nOvf > OVF_CAP) nOvf = OVF_CAP;
    int total = nOvf * 32;
    for (int idx = blockIdx.x * 256 + threadIdx.x; idx < total; idx += gridDim.x * 256) {
        int e = idx >> 5;
        int c = idx & 31;
        int r = ovfRow[e];
        int col = ovfCol[e];
        float v = ovfVal[e];
        uint2 u = *(const uint2*)(y + ((size_t)col << 7) + c * 4);
        atomicAdd(&out[(size_t)r * D + c * 4 + 0], v * bflo(u.x));
        atomicAdd(&out[(size_t)r * D + c * 4 + 1], v * bfhi(u.x));
        atomicAdd(&out[(size_t)r * D + c * 4 + 2], v * bflo(u.y));
        atomicAdd(&out[(size_t)r * D + c * 4 + 3], v * bfhi(u.y));
    }
}

// ---------------- launch ----------------
extern "C" void kernel_launch(void* const* d_in, const int* in_sizes, int n_in,
                              void* d_out, int out_size, void* d_ws, size_t ws_size,
                              hipStream_t stream) {
    const float* x = (const float*)d_in[0];
    const float* w = (const float*)d_in[1];
    const float* bias = (const float*)d_in[2];
    const float* ev = (const float*)d_in[3];
    const int* row = (const int*)d_in[4];
    const int* col = (const int*)d_in[5];
    float* out = (float*)d_out;

    size_t off = 0;
    auto carve = [&](size_t bytes) -> void* {
        void* p = (char*)d_ws + off;
        off += (bytes + 255) & ~(size_t)255;
        return p;
    };
    ushort* y = (ushort*)carve((size_t)N_NODES * D * sizeof(ushort));
    uint2* es0 = (uint2*)carve((size_t)NB * BCAP * sizeof(uint2));
    int* bucketCnt = (int*)carve((NB + 1) * sizeof(int));  // [NB] = ovfCnt
    int* ovfCnt = bucketCnt + NB;
    int* ovfRow = (int*)carve(OVF_CAP * sizeof(int));
    int* ovfCol = (int*)carve(OVF_CAP * sizeof(int));
    float* ovfVal = (float*)carve(OVF_CAP * sizeof(float));

    gemm_xw<<<782, 256, 0, stream>>>(x, w, y, bucketCnt);
    partition_edges<<<NCHUNKS, 256, 0, stream>>>(ev, row, col, bucketCnt, es0,
                                                 ovfCnt, ovfRow, ovfCol, ovfVal);
    ell_spmm<<<NSLICE, 256, 0, stream>>>(es0, bucketCnt, y, bias, out,
                                         ovfCnt, ovfRow, ovfCol, ovfVal);
    ovf_fix<<<16, 256, 0, stream>>>(y, ovfRow, ovfCol, ovfVal, ovfCnt, out);
}